// Round 3
// baseline (596.248 us; speedup 1.0000x reference)
//
#include <hip/hip_runtime.h>

// MoE SwiGLU gather, bf16 MFMA grouped GEMM. R6: barrier-free streaming.
// Key R5 evidence: L3-warm replays (FETCH~0) ran the SAME 100us as
// 125MB-fetch replays -> pure latency-bound; the 8-wave barrier cadence
// serializes every chunk at ~1 memory latency. R6 removes ALL barriers:
//  - Phase 1: both operands are k-contiguous per lane -> direct
//    global->reg MFMA fragments, depth-2 register pipeline, no LDS.
//  - Phase 2: A direct from hbuf (bf16); w2 transposed per-wave through
//    a wave-private XOR-swizzled LDS tile (same-wave lgkm only).
//  - 5632 / 4096 independent waves; every wave free-runs.

#define NEXP 8
#define HDIM 2816
#define DDIM 1024
#define NPAIR 1024

typedef unsigned int uint;
typedef unsigned short ushort;
typedef __attribute__((ext_vector_type(8))) short bf16x8;
typedef __attribute__((ext_vector_type(4))) float fvec4;
typedef __attribute__((ext_vector_type(4))) uint uvec4;

__device__ __forceinline__ ushort f2bf(float f) {
    uint u = __builtin_bit_cast(uint, f);
    u += 0x7fff + ((u >> 16) & 1);          // RTNE
    return (ushort)(u >> 16);
}
__device__ __forceinline__ uint pack2(float lo, float hi) {
    return (uint)f2bf(lo) | ((uint)f2bf(hi) << 16);
}
__device__ __forceinline__ bf16x8 cvt8(fvec4 a, fvec4 b) {
    uvec4 v;
    v.x = pack2(a.x, a.y); v.y = pack2(a.z, a.w);
    v.z = pack2(b.x, b.y); v.w = pack2(b.z, b.w);
    return __builtin_bit_cast(bf16x8, v);
}

// ws: [0] counts 32B | [1024] lists 32KB | [65536] hbuf bf16 5.77MB
__global__ __launch_bounds__(1024) void route_kernel(const int* __restrict__ idx,
                                                     int* __restrict__ counts,
                                                     int* __restrict__ lists) {
    int p = threadIdx.x;
    if (p < NEXP) counts[p] = 0;     // ws re-poisoned every call
    __syncthreads();
    int e = idx[p];
    int pos = atomicAdd(&counts[e], 1);
    lists[e * NPAIR + pos] = p;
}

// ---------------- Phase 1: hbuf[p,h] = silu(x·w1)*(x·w3) ----------------
// grid (8, 88, 16) = (expert, 32-h tile, 64-m tile), block 256 = 4 waves
// (2m x 2h). Wave owns 32m x 16h x {w1,w3}, fully independent: direct
// per-lane fragment loads (A: x rows, B: w rows; both k-contiguous),
// fp32->bf16 in regs, depth-2 pipeline, ZERO barriers, zero LDS.
#define NCH1 32                 // K-steps of 32 over DDIM

__global__ __launch_bounds__(256, 4) void h_mfma(const float* __restrict__ x,
                       const float* __restrict__ w1,
                       const float* __restrict__ w3,
                       const int* __restrict__ counts,
                       const int* __restrict__ lists,
                       ushort* __restrict__ hb) {
    const int e = blockIdx.x;
    const int cnt = counts[e];
    const int m0 = blockIdx.z * 64;
    if (m0 >= cnt) return;
    const int h0 = blockIdx.y * 32;

    const int tid = threadIdx.x;
    const int wm = (tid >> 6) & 1;
    const int wh = tid >> 7;
    const int lane = tid & 63;
    const int l16 = lane & 15;
    const int quad = lane >> 4;
    const int mw = m0 + wm * 32;
    const int hw = h0 + wh * 16;

    const int* lst = lists + e * NPAIR;
    int r0 = mw + l16;       int rc0 = (r0 < cnt) ? r0 : (cnt - 1);
    int r1 = mw + 16 + l16;  int rc1 = (r1 < cnt) ? r1 : (cnt - 1);
    const float* xa0 = x + (size_t)(lst[rc0] >> 1) * DDIM + quad * 8;
    const float* xa1 = x + (size_t)(lst[rc1] >> 1) * DDIM + quad * 8;
    const float* bp1 = w1 + (size_t)e * HDIM * DDIM + (size_t)(hw + l16) * DDIM + quad * 8;
    const float* bp3 = w3 + (size_t)e * HDIM * DDIM + (size_t)(hw + l16) * DDIM + quad * 8;

    fvec4 pf[2][8];

#define H_ISSUE(S, K) do { \
    pf[S][0] = *(const fvec4*)(xa0 + (K));     pf[S][1] = *(const fvec4*)(xa0 + (K) + 4); \
    pf[S][2] = *(const fvec4*)(xa1 + (K));     pf[S][3] = *(const fvec4*)(xa1 + (K) + 4); \
    pf[S][4] = *(const fvec4*)(bp1 + (K));     pf[S][5] = *(const fvec4*)(bp1 + (K) + 4); \
    pf[S][6] = *(const fvec4*)(bp3 + (K));     pf[S][7] = *(const fvec4*)(bp3 + (K) + 4); \
} while (0)

    fvec4 acc[2][2];   // [mi][mat]
    #pragma unroll
    for (int i = 0; i < 2; ++i) { acc[i][0] = (fvec4)0.f; acc[i][1] = (fvec4)0.f; }

    H_ISSUE(0, 0);
    H_ISSUE(1, 32);

    // body T (set S=T&1): convert set S (vmcnt-waits only set S, issued
    // 2 bodies ago -> latency covered), reissue S for T+2, MFMA.
#define H_BODY(T, S) do { \
    bf16x8 a0 = cvt8(pf[S][0], pf[S][1]); \
    bf16x8 a1 = cvt8(pf[S][2], pf[S][3]); \
    bf16x8 b1 = cvt8(pf[S][4], pf[S][5]); \
    bf16x8 b3 = cvt8(pf[S][6], pf[S][7]); \
    if ((T) + 2 < NCH1) H_ISSUE(S, ((T) + 2) * 32); \
    acc[0][0] = __builtin_amdgcn_mfma_f32_16x16x32_bf16(a0, b1, acc[0][0], 0, 0, 0); \
    acc[0][1] = __builtin_amdgcn_mfma_f32_16x16x32_bf16(a0, b3, acc[0][1], 0, 0, 0); \
    acc[1][0] = __builtin_amdgcn_mfma_f32_16x16x32_bf16(a1, b1, acc[1][0], 0, 0, 0); \
    acc[1][1] = __builtin_amdgcn_mfma_f32_16x16x32_bf16(a1, b3, acc[1][1], 0, 0, 0); \
} while (0)

    for (int t = 0; t < NCH1; t += 2) {
        H_BODY(t, 0);
        H_BODY(t + 1, 1);
    }

    // epilogue: C/D col=l16, row=quad*4+r
    #pragma unroll
    for (int mi = 0; mi < 2; ++mi) {
        #pragma unroll
        for (int r = 0; r < 4; ++r) {
            int row = mw + mi * 16 + quad * 4 + r;
            if (row < cnt) {
                int p = lst[row];
                float a = acc[mi][0][r];
                float g = acc[mi][1][r];
                float s = a / (1.f + __expf(-a)) * g;
                hb[(size_t)p * HDIM + hw + l16] = f2bf(s);
            }
        }
    }
}

// ---------------- Phase 2: out[p,d] += hbuf[p,:]·w2[e,:,d] ----------------
// grid (8, 32, 32) = (expert, 32-d tile, 16 mtile x 2 splitK), block 256
// = 4 waves (2m x 2d). Wave owns 32m x 16d, K=1408 per split in 64-h
// chunks. A frags direct from hbuf (bf16, zero-copy). B tile 16d x 64h
// transposed per-wave through private LDS: coalesced row loads (lane ->
// one w2 row, 64B), f2bf, scatter ds_write_b16 into a granule-XOR
// swizzled [d][64] tile (writes land 128B-linear per op; b128 frag reads
// spread all 8 granule columns -> all 32 banks busy). Same-wave LDS ->
// lgkmcnt only, ZERO barriers. fp32 atomic reduce into zeroed out.
#define NCH2 ((HDIM / 2) / 64)   // 22

__global__ __launch_bounds__(256, 4) void out_mfma(const float* __restrict__ w2,
                         const int* __restrict__ counts,
                         const int* __restrict__ lists,
                         const ushort* __restrict__ hb,
                         float* __restrict__ out) {
    const int e = blockIdx.x;
    const int cnt = counts[e];
    const int mb = blockIdx.z >> 1;
    const int sk = blockIdx.z & 1;
    const int m0 = mb * 64;
    if (m0 >= cnt) return;
    const int n0 = blockIdx.y * 32;
    const int kbase = sk * (HDIM / 2);      // 1408 per split

    __shared__ ushort sB[4][16 * 64];       // wave-private [d][k] swizzled

    const int tid = threadIdx.x;
    const int wid = tid >> 6;
    const int wm = wid & 1;
    const int wd = wid >> 1;
    const int lane = tid & 63;
    const int l16 = lane & 15;
    const int quad = lane >> 4;
    const int lg = lane >> 3;               // granule of this lane's k
    const int lo = lane & 7;                // offset within granule
    const int mw = m0 + wm * 32;
    const int dw = n0 + wd * 16;

    const int* lst = lists + e * NPAIR;
    int r0 = mw + l16;       int rc0 = (r0 < cnt) ? r0 : (cnt - 1);
    int r1 = mw + 16 + l16;  int rc1 = (r1 < cnt) ? r1 : (cnt - 1);
    const ushort* ha0 = hb + (size_t)lst[rc0] * HDIM + kbase + quad * 8;
    const ushort* ha1 = hb + (size_t)lst[rc1] * HDIM + kbase + quad * 8;
    // lane covers w2 row h = kbase + chunk*64 + lane, 16 d-floats (64B)
    const float* bp = w2 + (size_t)e * HDIM * DDIM + (size_t)(kbase + lane) * DDIM + dw;

    uvec4 pa[2][4];
    fvec4 pb[2][4];

#define O_ISSUE(S, C) do { \
    const ushort* qa0 = ha0 + (C) * 64; \
    const ushort* qa1 = ha1 + (C) * 64; \
    pa[S][0] = *(const uvec4*)qa0;        pa[S][1] = *(const uvec4*)(qa0 + 32); \
    pa[S][2] = *(const uvec4*)qa1;        pa[S][3] = *(const uvec4*)(qa1 + 32); \
    const float* qb = bp + (size_t)(C) * 64 * DDIM; \
    pb[S][0] = *(const fvec4*)qb;         pb[S][1] = *(const fvec4*)(qb + 4); \
    pb[S][2] = *(const fvec4*)(qb + 8);   pb[S][3] = *(const fvec4*)(qb + 12); \
} while (0)

    ushort* myB = &sB[wid][0];

    fvec4 acc[2];
    acc[0] = (fvec4)0.f; acc[1] = (fvec4)0.f;

    O_ISSUE(0, 0);
    O_ISSUE(1, 1);

    // swizzle: element (d,k) at d*64 + (((k>>3) ^ (d&7))<<3) + (k&7)
#define O_BODY(T, S) do { \
    _Pragma("unroll") \
    for (int j = 0; j < 16; ++j) \
        myB[j * 64 + (((lg ^ j) & 7) << 3) + lo] = f2bf(pb[S][j >> 2][j & 3]); \
    bf16x8 a00 = __builtin_bit_cast(bf16x8, pa[S][0]); \
    bf16x8 a01 = __builtin_bit_cast(bf16x8, pa[S][1]); \
    bf16x8 a10 = __builtin_bit_cast(bf16x8, pa[S][2]); \
    bf16x8 a11 = __builtin_bit_cast(bf16x8, pa[S][3]); \
    if ((T) + 2 < NCH2) O_ISSUE(S, (T) + 2); \
    bf16x8 b0 = *(const bf16x8*)&myB[l16 * 64 + ((((0 + quad) ^ l16) & 7) << 3)]; \
    bf16x8 b1 = *(const bf16x8*)&myB[l16 * 64 + ((((4 + quad) ^ l16) & 7) << 3)]; \
    acc[0] = __builtin_amdgcn_mfma_f32_16x16x32_bf16(a00, b0, acc[0], 0, 0, 0); \
    acc[1] = __builtin_amdgcn_mfma_f32_16x16x32_bf16(a10, b0, acc[1], 0, 0, 0); \
    acc[0] = __builtin_amdgcn_mfma_f32_16x16x32_bf16(a01, b1, acc[0], 0, 0, 0); \
    acc[1] = __builtin_amdgcn_mfma_f32_16x16x32_bf16(a11, b1, acc[1], 0, 0, 0); \
} while (0)

    for (int t = 0; t < NCH2; t += 2) {     // 22, even
        O_BODY(t, 0);
        O_BODY(t + 1, 1);
    }

    #pragma unroll
    for (int mi = 0; mi < 2; ++mi) {
        #pragma unroll
        for (int r = 0; r < 4; ++r) {
            int row = mw + mi * 16 + quad * 4 + r;
            if (row < cnt) {
                int p = lst[row];
                atomicAdd(&out[(size_t)p * DDIM + dw + l16], acc[mi][r]);
            }
        }
    }
}

extern "C" void kernel_launch(void* const* d_in, const int* in_sizes, int n_in,
                              void* d_out, int out_size, void* d_ws, size_t ws_size,
                              hipStream_t stream) {
    const float* x   = (const float*)d_in[0];
    const int*   idx = (const int*)d_in[1];
    const float* w1  = (const float*)d_in[2];
    const float* w2  = (const float*)d_in[3];
    const float* w3  = (const float*)d_in[4];
    float* out = (float*)d_out;

    char* ws = (char*)d_ws;
    int*    counts = (int*)ws;
    int*    lists  = (int*)(ws + 1024);
    ushort* hbuf   = (ushort*)(ws + 65536);

    hipMemsetAsync(out, 0, (size_t)out_size * sizeof(float), stream);
    route_kernel<<<1, NPAIR, 0, stream>>>(idx, counts, lists);
    h_mfma<<<dim3(NEXP, HDIM / 32, NPAIR / 64), 256, 0, stream>>>(
        x, w1, w3, counts, lists, hbuf);
    out_mfma<<<dim3(NEXP, DDIM / 32, (NPAIR / 64) * 2), 256, 0, stream>>>(
        w2, counts, lists, hbuf, out);
}

// Round 4
// 465.097 us; speedup vs baseline: 1.2820x; 1.2820x over previous
//
#include <hip/hip_runtime.h>

// MoE SwiGLU gather, bf16 MFMA grouped GEMM. R7: barrier-free phase 1,
// spill-proofed. R6's 272us was scratch: WRITE_SIZE 70MB (vs 5.8 legit),
// VGPR=64 with a ~110-reg pipeline -> pf[2][8] demoted to scratch.
// Fixes: named scalar fvec4s (token-pasted), peeled tail (no runtime
// issue guard), launch_bounds(256,2) (no occupancy-driven reg cap).
// Phase 2 reverted to R5's barriered version (never the top dispatch).

#define NEXP 8
#define HDIM 2816
#define DDIM 1024
#define NPAIR 1024

typedef unsigned int uint;
typedef unsigned short ushort;
typedef __attribute__((ext_vector_type(8))) short bf16x8;
typedef __attribute__((ext_vector_type(4))) float fvec4;
typedef __attribute__((ext_vector_type(4))) uint uvec4;

__device__ __forceinline__ ushort f2bf(float f) {
    uint u = __builtin_bit_cast(uint, f);
    u += 0x7fff + ((u >> 16) & 1);          // RTNE
    return (ushort)(u >> 16);
}
__device__ __forceinline__ uint pack2(float lo, float hi) {
    return (uint)f2bf(lo) | ((uint)f2bf(hi) << 16);
}
__device__ __forceinline__ uvec4 pack8(fvec4 a, fvec4 b) {
    uvec4 v;
    v.x = pack2(a.x, a.y); v.y = pack2(a.z, a.w);
    v.z = pack2(b.x, b.y); v.w = pack2(b.z, b.w);
    return v;
}
__device__ __forceinline__ bf16x8 cvt8(fvec4 a, fvec4 b) {
    return __builtin_bit_cast(bf16x8, pack8(a, b));
}

// LDS-only workgroup barrier (loads stay in flight across it).
__device__ __forceinline__ void wg_sync_lds() {
    __builtin_amdgcn_sched_barrier(0);
    asm volatile("s_waitcnt lgkmcnt(0)" ::: "memory");
    __builtin_amdgcn_s_barrier();
    __builtin_amdgcn_sched_barrier(0);
}

// ws: [0] counts 32B | [1024] lists 32KB | [65536] hbuf bf16 5.77MB
__global__ __launch_bounds__(1024) void route_kernel(const int* __restrict__ idx,
                                                     int* __restrict__ counts,
                                                     int* __restrict__ lists) {
    int p = threadIdx.x;
    if (p < NEXP) counts[p] = 0;     // ws re-poisoned every call
    __syncthreads();
    int e = idx[p];
    int pos = atomicAdd(&counts[e], 1);
    lists[e * NPAIR + pos] = p;
}

// ---------------- Phase 1: hbuf[p,h] = silu(x·w1)*(x·w3) ----------------
// grid (8, 88, 16) = (expert, 32-h tile, 64-m tile), block 256 = 4 waves
// (2m x 2h). Wave owns 32m x 16h x {w1,w3}, fully independent: direct
// per-lane fragment loads (both operands k-contiguous per lane),
// fp32->bf16 in regs, depth-2 NAMED-register pipeline, zero barriers,
// zero LDS. 5632 waves free-run; ~4 resident/SIMD at ~110 VGPR.
#define NCH1 32                 // K-steps of 32 over DDIM

__global__ __launch_bounds__(256, 2) void h_mfma(const float* __restrict__ x,
                       const float* __restrict__ w1,
                       const float* __restrict__ w3,
                       const int* __restrict__ counts,
                       const int* __restrict__ lists,
                       ushort* __restrict__ hb) {
    const int e = blockIdx.x;
    const int cnt = counts[e];
    const int m0 = blockIdx.z * 64;
    if (m0 >= cnt) return;
    const int h0 = blockIdx.y * 32;

    const int tid = threadIdx.x;
    const int wm = (tid >> 6) & 1;
    const int wh = tid >> 7;
    const int lane = tid & 63;
    const int l16 = lane & 15;
    const int quad = lane >> 4;
    const int mw = m0 + wm * 32;
    const int hw = h0 + wh * 16;

    const int* lst = lists + e * NPAIR;
    int r0 = mw + l16;       int rc0 = (r0 < cnt) ? r0 : (cnt - 1);
    int r1 = mw + 16 + l16;  int rc1 = (r1 < cnt) ? r1 : (cnt - 1);
    const float* xa0 = x + (size_t)(lst[rc0] >> 1) * DDIM + quad * 8;
    const float* xa1 = x + (size_t)(lst[rc1] >> 1) * DDIM + quad * 8;
    const float* bp1 = w1 + (size_t)e * HDIM * DDIM + (size_t)(hw + l16) * DDIM + quad * 8;
    const float* bp3 = w3 + (size_t)e * HDIM * DDIM + (size_t)(hw + l16) * DDIM + quad * 8;

    // depth-2 pipeline state: 16 NAMED fvec4 (spill-proof, no arrays)
    fvec4 a0lo0, a0hi0, a1lo0, a1hi0, b1lo0, b1hi0, b3lo0, b3hi0;
    fvec4 a0lo1, a0hi1, a1lo1, a1hi1, b1lo1, b1hi1, b3lo1, b3hi1;

#define H_ISSUE(S, KO) do { \
    a0lo##S = *(const fvec4*)(xa0 + (KO)); a0hi##S = *(const fvec4*)(xa0 + (KO) + 4); \
    a1lo##S = *(const fvec4*)(xa1 + (KO)); a1hi##S = *(const fvec4*)(xa1 + (KO) + 4); \
    b1lo##S = *(const fvec4*)(bp1 + (KO)); b1hi##S = *(const fvec4*)(bp1 + (KO) + 4); \
    b3lo##S = *(const fvec4*)(bp3 + (KO)); b3hi##S = *(const fvec4*)(bp3 + (KO) + 4); \
} while (0)

    fvec4 acc00 = (fvec4)0.f, acc01 = (fvec4)0.f;
    fvec4 acc10 = (fvec4)0.f, acc11 = (fvec4)0.f;

#define H_MFMA(S) do { \
    bf16x8 fa0 = cvt8(a0lo##S, a0hi##S); \
    bf16x8 fa1 = cvt8(a1lo##S, a1hi##S); \
    bf16x8 fb1 = cvt8(b1lo##S, b1hi##S); \
    bf16x8 fb3 = cvt8(b3lo##S, b3hi##S); \
    acc00 = __builtin_amdgcn_mfma_f32_16x16x32_bf16(fa0, fb1, acc00, 0, 0, 0); \
    acc01 = __builtin_amdgcn_mfma_f32_16x16x32_bf16(fa0, fb3, acc01, 0, 0, 0); \
    acc10 = __builtin_amdgcn_mfma_f32_16x16x32_bf16(fa1, fb1, acc10, 0, 0, 0); \
    acc11 = __builtin_amdgcn_mfma_f32_16x16x32_bf16(fa1, fb3, acc11, 0, 0, 0); \
} while (0)

    H_ISSUE(0, 0);
    H_ISSUE(1, 32);

    // steady state: bodies t,t+1 consume sets 0,1 and reissue t+2,t+3.
    int t = 0;
    for (; t < NCH1 - 4; t += 2) {
        {   // body t (set 0): convert first, then reissue, then MFMA
            bf16x8 fa0 = cvt8(a0lo0, a0hi0), fa1 = cvt8(a1lo0, a1hi0);
            bf16x8 fb1 = cvt8(b1lo0, b1hi0), fb3 = cvt8(b3lo0, b3hi0);
            H_ISSUE(0, (t + 2) * 32);
            acc00 = __builtin_amdgcn_mfma_f32_16x16x32_bf16(fa0, fb1, acc00, 0, 0, 0);
            acc01 = __builtin_amdgcn_mfma_f32_16x16x32_bf16(fa0, fb3, acc01, 0, 0, 0);
            acc10 = __builtin_amdgcn_mfma_f32_16x16x32_bf16(fa1, fb1, acc10, 0, 0, 0);
            acc11 = __builtin_amdgcn_mfma_f32_16x16x32_bf16(fa1, fb3, acc11, 0, 0, 0);
        }
        {   // body t+1 (set 1)
            bf16x8 fa0 = cvt8(a0lo1, a0hi1), fa1 = cvt8(a1lo1, a1hi1);
            bf16x8 fb1 = cvt8(b1lo1, b1hi1), fb3 = cvt8(b3lo1, b3hi1);
            H_ISSUE(1, (t + 3) * 32);
            acc00 = __builtin_amdgcn_mfma_f32_16x16x32_bf16(fa0, fb1, acc00, 0, 0, 0);
            acc01 = __builtin_amdgcn_mfma_f32_16x16x32_bf16(fa0, fb3, acc01, 0, 0, 0);
            acc10 = __builtin_amdgcn_mfma_f32_16x16x32_bf16(fa1, fb1, acc10, 0, 0, 0);
            acc11 = __builtin_amdgcn_mfma_f32_16x16x32_bf16(fa1, fb3, acc11, 0, 0, 0);
        }
    }
    // t == NCH1-4: bodies NCH1-4 .. NCH1-1, last two without reissue.
    {
        bf16x8 fa0 = cvt8(a0lo0, a0hi0), fa1 = cvt8(a1lo0, a1hi0);
        bf16x8 fb1 = cvt8(b1lo0, b1hi0), fb3 = cvt8(b3lo0, b3hi0);
        H_ISSUE(0, (NCH1 - 2) * 32);
        acc00 = __builtin_amdgcn_mfma_f32_16x16x32_bf16(fa0, fb1, acc00, 0, 0, 0);
        acc01 = __builtin_amdgcn_mfma_f32_16x16x32_bf16(fa0, fb3, acc01, 0, 0, 0);
        acc10 = __builtin_amdgcn_mfma_f32_16x16x32_bf16(fa1, fb1, acc10, 0, 0, 0);
        acc11 = __builtin_amdgcn_mfma_f32_16x16x32_bf16(fa1, fb3, acc11, 0, 0, 0);
    }
    {
        bf16x8 fa0 = cvt8(a0lo1, a0hi1), fa1 = cvt8(a1lo1, a1hi1);
        bf16x8 fb1 = cvt8(b1lo1, b1hi1), fb3 = cvt8(b3lo1, b3hi1);
        H_ISSUE(1, (NCH1 - 1) * 32);
        acc00 = __builtin_amdgcn_mfma_f32_16x16x32_bf16(fa0, fb1, acc00, 0, 0, 0);
        acc01 = __builtin_amdgcn_mfma_f32_16x16x32_bf16(fa0, fb3, acc01, 0, 0, 0);
        acc10 = __builtin_amdgcn_mfma_f32_16x16x32_bf16(fa1, fb1, acc10, 0, 0, 0);
        acc11 = __builtin_amdgcn_mfma_f32_16x16x32_bf16(fa1, fb3, acc11, 0, 0, 0);
    }
    H_MFMA(0);
    H_MFMA(1);

    // epilogue: C/D col=l16, row=quad*4+r
    fvec4 accA[2][2];
    accA[0][0] = acc00; accA[0][1] = acc01; accA[1][0] = acc10; accA[1][1] = acc11;
    #pragma unroll
    for (int mi = 0; mi < 2; ++mi) {
        #pragma unroll
        for (int r = 0; r < 4; ++r) {
            int row = mw + mi * 16 + quad * 4 + r;
            if (row < cnt) {
                int p = lst[row];
                float a = accA[mi][0][r];
                float g = accA[mi][1][r];
                float s = a / (1.f + __expf(-a)) * g;
                hb[(size_t)p * HDIM + hw + l16] = f2bf(s);
            }
        }
    }
}

// ---------------- Phase 2: out[p,d] += hbuf[p,:]·w2[e,:,d] ----------------
// R5 version (barriered, known-good): grid (8, 32, 32) = (expert, 32-d
// tile, mblock*4 + splitK), block 512, waves 4m x 2d, K-chunk 64,
// 11 chunks per split, fp32 atomic reduce.
#define LDK 68
#define NCH2 ((HDIM / 4) / 64)   // 11

__global__ __launch_bounds__(512, 4) void out_mfma(const float* __restrict__ w2,
                         const int* __restrict__ counts,
                         const int* __restrict__ lists,
                         const ushort* __restrict__ hb,
                         float* __restrict__ out) {
    const int e = blockIdx.x;
    const int cnt = counts[e];
    const int mb = blockIdx.z >> 2;
    const int sk = blockIdx.z & 3;
    const int m0 = mb * 128;
    if (m0 >= cnt) return;
    const int n0 = blockIdx.y * 32;
    const int kbase = sk * (HDIM / 4);      // 704 per split

    __shared__ ushort sA[2][128 * LDK];
    __shared__ ushort sB[2][32 * LDK];
    __shared__ int sPairC[128];
    __shared__ int sPairS[128];

    const int tid = threadIdx.x;
    if (tid < 128) {
        int m = m0 + tid;
        int mc = (m < cnt) ? m : (cnt - 1);
        int p = lists[e * NPAIR + mc];
        sPairC[tid] = p;
        sPairS[tid] = (m < cnt) ? p : -1;
    }
    wg_sync_lds();

    const int arow = tid >> 2;
    const int akg  = (tid & 3) * 16;        // ushort offset
    const ushort* aSrc = hb + (size_t)sPairC[arow] * HDIM + kbase + akg;

    const int bkp = (tid >> 3) & 31;        // k pair 0..31
    const int bdg = tid & 7;                // d group (4 floats)
    const float* bSrc = w2 + (size_t)e * HDIM * DDIM
                        + (size_t)(kbase + 2 * bkp) * DDIM + n0 + bdg * 4;

    uvec4 pfA[2][2];
    fvec4 pfB[2][2];

#define P2_ISSUE(S, KC) do { \
    const ushort* qa = aSrc + (KC) * 64; \
    pfA[S][0] = *(const uvec4*)qa; \
    pfA[S][1] = *(const uvec4*)(qa + 8); \
    if (tid < 256) { \
        const float* qb = bSrc + (size_t)(KC) * 64 * DDIM; \
        pfB[S][0] = *(const fvec4*)qb; \
        pfB[S][1] = *(const fvec4*)(qb + DDIM); \
    } \
} while (0)

#define P2_STAGE(S, B) do { \
    *(uvec4*)&sA[B][arow * LDK + akg] = pfA[S][0]; \
    *(uvec4*)&sA[B][arow * LDK + akg + 8] = pfA[S][1]; \
    if (tid < 256) { \
        _Pragma("unroll") \
        for (int j = 0; j < 4; ++j) \
            *(uint*)&sB[B][(bdg * 4 + j) * LDK + bkp * 2] = pack2(pfB[S][0][j], pfB[S][1][j]); \
    } \
} while (0)

    const int w = tid >> 6;
    const int wm = w & 3;
    const int wh = w >> 2;
    const int lane = tid & 63;
    const int l16 = lane & 15;
    const int quad = lane >> 4;

    const int ar0 = (wm * 32 + l16) * LDK + quad * 8;
    const int br0 = (wh * 16 + l16) * LDK + quad * 8;

    fvec4 acc[2];
    acc[0] = (fvec4)0.f; acc[1] = (fvec4)0.f;

    P2_ISSUE(0, 0);
    P2_ISSUE(1, 1);
    P2_STAGE(0, 0);
    wg_sync_lds();

#define P2_BODY(T, CUR) do { \
    bf16x8 a00 = *(const bf16x8*)&sA[CUR][ar0]; \
    bf16x8 a01 = *(const bf16x8*)&sA[CUR][ar0 + 32]; \
    bf16x8 a10 = *(const bf16x8*)&sA[CUR][ar0 + 16 * LDK]; \
    bf16x8 a11 = *(const bf16x8*)&sA[CUR][ar0 + 16 * LDK + 32]; \
    bf16x8 b0 = *(const bf16x8*)&sB[CUR][br0]; \
    bf16x8 b1 = *(const bf16x8*)&sB[CUR][br0 + 32]; \
    if ((T) + 2 < NCH2) P2_ISSUE(CUR, (T) + 2); \
    acc[0] = __builtin_amdgcn_mfma_f32_16x16x32_bf16(a00, b0, acc[0], 0, 0, 0); \
    acc[1] = __builtin_amdgcn_mfma_f32_16x16x32_bf16(a10, b0, acc[1], 0, 0, 0); \
    acc[0] = __builtin_amdgcn_mfma_f32_16x16x32_bf16(a01, b1, acc[0], 0, 0, 0); \
    acc[1] = __builtin_amdgcn_mfma_f32_16x16x32_bf16(a11, b1, acc[1], 0, 0, 0); \
    if ((T) + 1 < NCH2) { \
        P2_STAGE(CUR ^ 1, CUR ^ 1); \
        wg_sync_lds(); \
    } \
} while (0)

    for (int t = 0; t < NCH2; t += 2) {     // 11, odd
        P2_BODY(t, 0);
        if (t + 1 < NCH2) P2_BODY(t + 1, 1);
    }

    #pragma unroll
    for (int mi = 0; mi < 2; ++mi) {
        #pragma unroll
        for (int r = 0; r < 4; ++r) {
            int mrow = wm * 32 + mi * 16 + quad * 4 + r;
            int p = sPairS[mrow];
            if (p >= 0)
                atomicAdd(&out[(size_t)p * DDIM + n0 + wh * 16 + l16], acc[mi][r]);
        }
    }
}

extern "C" void kernel_launch(void* const* d_in, const int* in_sizes, int n_in,
                              void* d_out, int out_size, void* d_ws, size_t ws_size,
                              hipStream_t stream) {
    const float* x   = (const float*)d_in[0];
    const int*   idx = (const int*)d_in[1];
    const float* w1  = (const float*)d_in[2];
    const float* w2  = (const float*)d_in[3];
    const float* w3  = (const float*)d_in[4];
    float* out = (float*)d_out;

    char* ws = (char*)d_ws;
    int*    counts = (int*)ws;
    int*    lists  = (int*)(ws + 1024);
    ushort* hbuf   = (ushort*)(ws + 65536);

    hipMemsetAsync(out, 0, (size_t)out_size * sizeof(float), stream);
    route_kernel<<<1, NPAIR, 0, stream>>>(idx, counts, lists);
    h_mfma<<<dim3(NEXP, HDIM / 32, NPAIR / 64), 256, 0, stream>>>(
        x, w1, w3, counts, lists, hbuf);
    out_mfma<<<dim3(NEXP, DDIM / 32, (NPAIR / 128) * 4), 512, 0, stream>>>(
        w2, counts, lists, hbuf, out);
}

// Round 5
// 334.151 us; speedup vs baseline: 1.7844x; 1.3919x over previous
//
#include <hip/hip_runtime.h>

// MoE SwiGLU gather, bf16 MFMA grouped GEMM. R8: DRAM-burst attack.
// Evidence R3-R7: dur ~= HBM_bytes / 1.1 TB/s across ALL structures;
// all pipes idle. Weight reads were 128-256B column-chunks of 4KB rows
// at 4KB stride -> DRAM page thrash caps HBM at ~15-20% of peak.
// R8 phase 1: BK=256 (1KB per row per chunk); staging mapped so ONE
// instruction = 64 lanes x 16B = one contiguous 1KB span (m13 pattern).
// BN=32 (w1+w3), BM=128, 4 chunks, LDS bf16 dbuf 66KB (2 blocks/CU),
// lgkm-only barrier per chunk, A (L2-resident x) per-lane direct with
// rolling 4-kstep lookahead. Phase 2 unchanged (known-good R5).

#define NEXP 8
#define HDIM 2816
#define DDIM 1024
#define NPAIR 1024

typedef unsigned int uint;
typedef unsigned short ushort;
typedef __attribute__((ext_vector_type(8))) short bf16x8;
typedef __attribute__((ext_vector_type(4))) float fvec4;
typedef __attribute__((ext_vector_type(4))) uint uvec4;
typedef __attribute__((ext_vector_type(2))) uint uvec2;

__device__ __forceinline__ ushort f2bf(float f) {
    uint u = __builtin_bit_cast(uint, f);
    u += 0x7fff + ((u >> 16) & 1);          // RTNE
    return (ushort)(u >> 16);
}
__device__ __forceinline__ uint pack2(float lo, float hi) {
    return (uint)f2bf(lo) | ((uint)f2bf(hi) << 16);
}
__device__ __forceinline__ uvec4 pack8(fvec4 a, fvec4 b) {
    uvec4 v;
    v.x = pack2(a.x, a.y); v.y = pack2(a.z, a.w);
    v.z = pack2(b.x, b.y); v.w = pack2(b.z, b.w);
    return v;
}
__device__ __forceinline__ bf16x8 cvt8(fvec4 a, fvec4 b) {
    return __builtin_bit_cast(bf16x8, pack8(a, b));
}

// LDS-only workgroup barrier (global loads stay in flight across it).
__device__ __forceinline__ void wg_sync_lds() {
    __builtin_amdgcn_sched_barrier(0);
    asm volatile("s_waitcnt lgkmcnt(0)" ::: "memory");
    __builtin_amdgcn_s_barrier();
    __builtin_amdgcn_sched_barrier(0);
}

// ws: [0] counts 32B | [1024] lists 32KB | [65536] hbuf bf16 5.77MB
__global__ __launch_bounds__(1024) void route_kernel(const int* __restrict__ idx,
                                                     int* __restrict__ counts,
                                                     int* __restrict__ lists) {
    int p = threadIdx.x;
    if (p < NEXP) counts[p] = 0;     // ws re-poisoned every call
    __syncthreads();
    int e = idx[p];
    int pos = atomicAdd(&counts[e], 1);
    lists[e * NPAIR + pos] = p;
}

// ---------------- Phase 1: hbuf[p,h] = silu(x·w1)*(x·w3) ----------------
// grid (8, 88, 8) = (expert, 32-h tile, 128-m tile), block 512 = 8 waves,
// wave w owns m rows [16w,16w+16) x all 32 h x both mats.
// K-chunk 256 floats (1KB/row burst); 4 chunks; staging: wave w, instr j
// reads row h0+w+8j as ONE contiguous 1KB span (lane*16B).
#define LDB1 264   // 256 + 8 ushort pad: 528B row stride, 2-way banks only

__global__ __launch_bounds__(512, 4) void h_mfma(const float* __restrict__ x,
                       const float* __restrict__ w1,
                       const float* __restrict__ w3,
                       const int* __restrict__ counts,
                       const int* __restrict__ lists,
                       ushort* __restrict__ hb) {
    const int e = blockIdx.x;
    const int cnt = counts[e];
    const int m0 = blockIdx.z * 128;
    if (m0 >= cnt) return;
    const int h0 = blockIdx.y * 32;

    __shared__ ushort sB[2][2][32 * LDB1];   // [buf][mat][row*LDB1+k] 66KB

    const int tid = threadIdx.x;
    const int w = tid >> 6;
    const int lane = tid & 63;
    const int l16 = lane & 15;
    const int quad = lane >> 4;

    const int* lst = lists + e * NPAIR;
    int arow = m0 + w * 16 + l16;
    int arc = (arow < cnt) ? arow : (cnt - 1);
    const float* xa = x + (size_t)(lst[arc] >> 1) * DDIM + quad * 8;   // TOPK=2

    // staging: wave w stages rows {h0+w+8j}; lane covers [lane*16B, +16B)
    const float* stB1 = w1 + (size_t)e * HDIM * DDIM + (size_t)(h0 + w) * DDIM + lane * 4;
    const float* stB3 = w3 + (size_t)e * HDIM * DDIM + (size_t)(h0 + w) * DDIM + lane * 4;

    fvec4 pb0, pb1, pb2, pb3, pb4, pb5, pb6, pb7;              // B prefetch (32 VGPR)
    fvec4 pa0x, pa0y, pa1x, pa1y, pa2x, pa2y, pa3x, pa3y;      // A rolling slots
    fvec4 acc00 = (fvec4)0.f, acc01 = (fvec4)0.f;              // [mat][hfrag]
    fvec4 acc10 = (fvec4)0.f, acc11 = (fvec4)0.f;

#define P1_ISSUE_B(KC) do { \
    pb0 = *(const fvec4*)(stB1 + (KC) * 256 + 0 * 8 * DDIM); \
    pb1 = *(const fvec4*)(stB1 + (KC) * 256 + 1 * 8 * DDIM); \
    pb2 = *(const fvec4*)(stB1 + (KC) * 256 + 2 * 8 * DDIM); \
    pb3 = *(const fvec4*)(stB1 + (KC) * 256 + 3 * 8 * DDIM); \
    pb4 = *(const fvec4*)(stB3 + (KC) * 256 + 0 * 8 * DDIM); \
    pb5 = *(const fvec4*)(stB3 + (KC) * 256 + 1 * 8 * DDIM); \
    pb6 = *(const fvec4*)(stB3 + (KC) * 256 + 2 * 8 * DDIM); \
    pb7 = *(const fvec4*)(stB3 + (KC) * 256 + 3 * 8 * DDIM); \
} while (0)

#define P1_WRITE_B(BUF) do { \
    *(uvec2*)&sB[BUF][0][(w +  0) * LDB1 + lane * 4] = (uvec2){pack2(pb0.x, pb0.y), pack2(pb0.z, pb0.w)}; \
    *(uvec2*)&sB[BUF][0][(w +  8) * LDB1 + lane * 4] = (uvec2){pack2(pb1.x, pb1.y), pack2(pb1.z, pb1.w)}; \
    *(uvec2*)&sB[BUF][0][(w + 16) * LDB1 + lane * 4] = (uvec2){pack2(pb2.x, pb2.y), pack2(pb2.z, pb2.w)}; \
    *(uvec2*)&sB[BUF][0][(w + 24) * LDB1 + lane * 4] = (uvec2){pack2(pb3.x, pb3.y), pack2(pb3.z, pb3.w)}; \
    *(uvec2*)&sB[BUF][1][(w +  0) * LDB1 + lane * 4] = (uvec2){pack2(pb4.x, pb4.y), pack2(pb4.z, pb4.w)}; \
    *(uvec2*)&sB[BUF][1][(w +  8) * LDB1 + lane * 4] = (uvec2){pack2(pb5.x, pb5.y), pack2(pb5.z, pb5.w)}; \
    *(uvec2*)&sB[BUF][1][(w + 16) * LDB1 + lane * 4] = (uvec2){pack2(pb6.x, pb6.y), pack2(pb6.z, pb6.w)}; \
    *(uvec2*)&sB[BUF][1][(w + 24) * LDB1 + lane * 4] = (uvec2){pack2(pb7.x, pb7.y), pack2(pb7.z, pb7.w)}; \
} while (0)

#define BFRAG(BUF, MAT, HF, KS) \
    (*(const bf16x8*)&sB[BUF][MAT][((HF) * 16 + l16) * LDB1 + (KS) * 32 + quad * 8])

    // kstep: consume A slot SL, reload it for global kstep RELK (lookahead 4)
#define P1_KSTEP(BUF, KS, SL, RELK) do { \
    bf16x8 af = cvt8(pa##SL##x, pa##SL##y); \
    bf16x8 b00 = BFRAG(BUF, 0, 0, KS); \
    bf16x8 b01 = BFRAG(BUF, 0, 1, KS); \
    bf16x8 b10 = BFRAG(BUF, 1, 0, KS); \
    bf16x8 b11 = BFRAG(BUF, 1, 1, KS); \
    if ((RELK) < 32) { \
        pa##SL##x = *(const fvec4*)(xa + (RELK) * 32); \
        pa##SL##y = *(const fvec4*)(xa + (RELK) * 32 + 4); \
    } \
    acc00 = __builtin_amdgcn_mfma_f32_16x16x32_bf16(af, b00, acc00, 0, 0, 0); \
    acc01 = __builtin_amdgcn_mfma_f32_16x16x32_bf16(af, b01, acc01, 0, 0, 0); \
    acc10 = __builtin_amdgcn_mfma_f32_16x16x32_bf16(af, b10, acc10, 0, 0, 0); \
    acc11 = __builtin_amdgcn_mfma_f32_16x16x32_bf16(af, b11, acc11, 0, 0, 0); \
} while (0)

#define P1_CHUNK(T, BUF) do { \
    P1_KSTEP(BUF, 0, 0, (T) * 8 + 4); \
    P1_KSTEP(BUF, 1, 1, (T) * 8 + 5); \
    P1_KSTEP(BUF, 2, 2, (T) * 8 + 6); \
    P1_KSTEP(BUF, 3, 3, (T) * 8 + 7); \
    P1_KSTEP(BUF, 4, 0, (T) * 8 + 8); \
    P1_KSTEP(BUF, 5, 1, (T) * 8 + 9); \
    P1_KSTEP(BUF, 6, 2, (T) * 8 + 10); \
    P1_KSTEP(BUF, 7, 3, (T) * 8 + 11); \
} while (0)

    P1_ISSUE_B(0);
    pa0x = *(const fvec4*)(xa +  0); pa0y = *(const fvec4*)(xa +  4);
    pa1x = *(const fvec4*)(xa + 32); pa1y = *(const fvec4*)(xa + 36);
    pa2x = *(const fvec4*)(xa + 64); pa2y = *(const fvec4*)(xa + 68);
    pa3x = *(const fvec4*)(xa + 96); pa3y = *(const fvec4*)(xa + 100);
    P1_WRITE_B(0);          // counted vmcnt: waits B set only
    P1_ISSUE_B(1);
    wg_sync_lds();

    P1_CHUNK(0, 0);
    P1_WRITE_B(1); P1_ISSUE_B(2); wg_sync_lds();
    P1_CHUNK(1, 1);
    P1_WRITE_B(0); P1_ISSUE_B(3); wg_sync_lds();
    P1_CHUNK(2, 0);
    P1_WRITE_B(1);                 wg_sync_lds();
    P1_CHUNK(3, 1);

    // epilogue: C/D col=l16 (h), row=quad*4+r (m)
    #pragma unroll
    for (int hf = 0; hf < 2; ++hf) {
        #pragma unroll
        for (int r = 0; r < 4; ++r) {
            int row = m0 + w * 16 + quad * 4 + r;
            if (row < cnt) {
                int p = lst[row];
                float a = (hf == 0) ? acc00[r] : acc01[r];
                float g = (hf == 0) ? acc10[r] : acc11[r];
                float s = a / (1.f + __expf(-a)) * g;
                hb[(size_t)p * HDIM + h0 + hf * 16 + l16] = f2bf(s);
            }
        }
    }
}

// ---------------- Phase 2: out[p,d] += hbuf[p,:]·w2[e,:,d] ----------------
// R5 version (known-good): grid (8, 32, 32) = (expert, 32-d tile,
// mblock*4 + splitK), block 512, waves 4m x 2d, K-chunk 64, 11 chunks
// per split, fp32 atomic reduce.
#define LDK 68
#define NCH2 ((HDIM / 4) / 64)   // 11

__global__ __launch_bounds__(512, 4) void out_mfma(const float* __restrict__ w2,
                         const int* __restrict__ counts,
                         const int* __restrict__ lists,
                         const ushort* __restrict__ hb,
                         float* __restrict__ out) {
    const int e = blockIdx.x;
    const int cnt = counts[e];
    const int mb = blockIdx.z >> 2;
    const int sk = blockIdx.z & 3;
    const int m0 = mb * 128;
    if (m0 >= cnt) return;
    const int n0 = blockIdx.y * 32;
    const int kbase = sk * (HDIM / 4);      // 704 per split

    __shared__ ushort sA[2][128 * LDK];
    __shared__ ushort sB[2][32 * LDK];
    __shared__ int sPairC[128];
    __shared__ int sPairS[128];

    const int tid = threadIdx.x;
    if (tid < 128) {
        int m = m0 + tid;
        int mc = (m < cnt) ? m : (cnt - 1);
        int p = lists[e * NPAIR + mc];
        sPairC[tid] = p;
        sPairS[tid] = (m < cnt) ? p : -1;
    }
    wg_sync_lds();

    const int arow = tid >> 2;
    const int akg  = (tid & 3) * 16;        // ushort offset
    const ushort* aSrc = hb + (size_t)sPairC[arow] * HDIM + kbase + akg;

    const int bkp = (tid >> 3) & 31;        // k pair 0..31
    const int bdg = tid & 7;                // d group (4 floats)
    const float* bSrc = w2 + (size_t)e * HDIM * DDIM
                        + (size_t)(kbase + 2 * bkp) * DDIM + n0 + bdg * 4;

    uvec4 pfA[2][2];
    fvec4 pfB[2][2];

#define P2_ISSUE(S, KC) do { \
    const ushort* qa = aSrc + (KC) * 64; \
    pfA[S][0] = *(const uvec4*)qa; \
    pfA[S][1] = *(const uvec4*)(qa + 8); \
    if (tid < 256) { \
        const float* qb = bSrc + (size_t)(KC) * 64 * DDIM; \
        pfB[S][0] = *(const fvec4*)qb; \
        pfB[S][1] = *(const fvec4*)(qb + DDIM); \
    } \
} while (0)

#define P2_STAGE(S, B) do { \
    *(uvec4*)&sA[B][arow * LDK + akg] = pfA[S][0]; \
    *(uvec4*)&sA[B][arow * LDK + akg + 8] = pfA[S][1]; \
    if (tid < 256) { \
        _Pragma("unroll") \
        for (int j = 0; j < 4; ++j) \
            *(uint*)&sB[B][(bdg * 4 + j) * LDK + bkp * 2] = pack2(pfB[S][0][j], pfB[S][1][j]); \
    } \
} while (0)

    const int w = tid >> 6;
    const int wm = w & 3;
    const int wh = w >> 2;
    const int lane = tid & 63;
    const int l16 = lane & 15;
    const int quad = lane >> 4;

    const int ar0 = (wm * 32 + l16) * LDK + quad * 8;
    const int br0 = (wh * 16 + l16) * LDK + quad * 8;

    fvec4 acc[2];
    acc[0] = (fvec4)0.f; acc[1] = (fvec4)0.f;

    P2_ISSUE(0, 0);
    P2_ISSUE(1, 1);
    P2_STAGE(0, 0);
    wg_sync_lds();

#define P2_BODY(T, CUR) do { \
    bf16x8 a00 = *(const bf16x8*)&sA[CUR][ar0]; \
    bf16x8 a01 = *(const bf16x8*)&sA[CUR][ar0 + 32]; \
    bf16x8 a10 = *(const bf16x8*)&sA[CUR][ar0 + 16 * LDK]; \
    bf16x8 a11 = *(const bf16x8*)&sA[CUR][ar0 + 16 * LDK + 32]; \
    bf16x8 b0 = *(const bf16x8*)&sB[CUR][br0]; \
    bf16x8 b1 = *(const bf16x8*)&sB[CUR][br0 + 32]; \
    if ((T) + 2 < NCH2) P2_ISSUE(CUR, (T) + 2); \
    acc[0] = __builtin_amdgcn_mfma_f32_16x16x32_bf16(a00, b0, acc[0], 0, 0, 0); \
    acc[1] = __builtin_amdgcn_mfma_f32_16x16x32_bf16(a10, b0, acc[1], 0, 0, 0); \
    acc[0] = __builtin_amdgcn_mfma_f32_16x16x32_bf16(a01, b1, acc[0], 0, 0, 0); \
    acc[1] = __builtin_amdgcn_mfma_f32_16x16x32_bf16(a11, b1, acc[1], 0, 0, 0); \
    if ((T) + 1 < NCH2) { \
        P2_STAGE(CUR ^ 1, CUR ^ 1); \
        wg_sync_lds(); \
    } \
} while (0)

    for (int t = 0; t < NCH2; t += 2) {     // 11, odd
        P2_BODY(t, 0);
        if (t + 1 < NCH2) P2_BODY(t + 1, 1);
    }

    #pragma unroll
    for (int mi = 0; mi < 2; ++mi) {
        #pragma unroll
        for (int r = 0; r < 4; ++r) {
            int mrow = wm * 32 + mi * 16 + quad * 4 + r;
            int p = sPairS[mrow];
            if (p >= 0)
                atomicAdd(&out[(size_t)p * DDIM + n0 + wh * 16 + l16], acc[mi][r]);
        }
    }
}

extern "C" void kernel_launch(void* const* d_in, const int* in_sizes, int n_in,
                              void* d_out, int out_size, void* d_ws, size_t ws_size,
                              hipStream_t stream) {
    const float* x   = (const float*)d_in[0];
    const int*   idx = (const int*)d_in[1];
    const float* w1  = (const float*)d_in[2];
    const float* w2  = (const float*)d_in[3];
    const float* w3  = (const float*)d_in[4];
    float* out = (float*)d_out;

    char* ws = (char*)d_ws;
    int*    counts = (int*)ws;
    int*    lists  = (int*)(ws + 1024);
    ushort* hbuf   = (ushort*)(ws + 65536);

    hipMemsetAsync(out, 0, (size_t)out_size * sizeof(float), stream);
    route_kernel<<<1, NPAIR, 0, stream>>>(idx, counts, lists);
    h_mfma<<<dim3(NEXP, HDIM / 32, NPAIR / 128), 512, 0, stream>>>(
        x, w1, w3, counts, lists, hbuf);
    out_mfma<<<dim3(NEXP, DDIM / 32, (NPAIR / 128) * 4), 512, 0, stream>>>(
        w2, counts, lists, hbuf, out);
}